// Round 4
// baseline (389.117 us; speedup 1.0000x reference)
//
#include <hip/hip_runtime.h>

#define B_TOT 4096
#define IN_W 323

typedef __attribute__((ext_vector_type(8))) short short8;
typedef __attribute__((ext_vector_type(4))) float f32x4;
typedef unsigned short u16;

#define MFMA16(a, b, c) __builtin_amdgcn_mfma_f32_16x16x32_bf16(a, b, c, 0, 0, 0)

__device__ __forceinline__ float sigmoidf_(float x) { return 1.0f / (1.0f + __expf(-x)); }

__device__ __forceinline__ u16 f2bf(float f) {
    unsigned int u = __float_as_uint(f);
    u += 0x7FFF + ((u >> 16) & 1);
    return (u16)(u >> 16);
}

union BF8 { u16 u[8]; short8 v; };

struct WS {
    u16 *oWb, *tgWb, *agWb, *hgWb, *g3W2b, *W1b, *fWb, *htldb;
    float *wsum, *preds, *cvec, *lg;
};

// ---- k0: weight transposes (row-major f32 [K][128] -> n-major bf16 [128][K]) + wsum ----
__global__ __launch_bounds__(256) void k0_prep(
    const float* __restrict__ oW, const float* __restrict__ tgW,
    const float* __restrict__ agW, const float* __restrict__ hgW,
    const float* __restrict__ g3W, const float* __restrict__ tw,
    const float* __restrict__ aw, const float* __restrict__ hw, WS w) {
    int bx = blockIdx.x, tid = threadIdx.x;
    if (bx == 88) {  // wsum: row-sums of gate3_W rows 256..405
        if (tid < 128) {
            int n = tid;
            float st = 0.f, sa = 0.f, sh = 0.f;
            for (int k = 0; k < 50; ++k) {
                st += g3W[(size_t)(256 + k) * 128 + n];
                sa += g3W[(size_t)(306 + k) * 128 + n];
                sh += g3W[(size_t)(356 + k) * 128 + n];
            }
            w.wsum[n] = st; w.wsum[128 + n] = sa; w.wsum[256 + n] = sh;
        }
        return;
    }
    __shared__ float s_t[32][132];
    const float* src; u16* dst; int K, k0;
    if (bx < 32) {
        int mat = bx >> 3; k0 = (bx & 7) * 32; K = 256;
        src = mat == 0 ? oW : mat == 1 ? tgW : mat == 2 ? agW : hgW;
        dst = mat == 0 ? w.oWb : mat == 1 ? w.tgWb : mat == 2 ? w.agWb : w.hgWb;
    } else {
        int i = bx - 32; int mat = i >> 2; k0 = (i & 3) * 32; K = 128;
        if (mat == 0) { src = g3W; dst = w.W1b; }
        else if (mat == 1) { src = g3W + 128 * 128; dst = w.g3W2b; }
        else {
            int f = mat - 2, g = f >> 2, r = f & 3;
            src = (g == 0 ? tw : g == 1 ? aw : hw) + (size_t)r * 129 * 128;
            dst = w.fWb + (size_t)f * 128 * 128;
        }
    }
#pragma unroll
    for (int jj = 0; jj < 4; ++jj) {
        int id = tid + jj * 256;
        int row = id >> 5, c4 = (id & 31) * 4;
        float4 v = *(const float4*)(src + (size_t)(k0 + row) * 128 + c4);
        s_t[row][c4] = v.x; s_t[row][c4 + 1] = v.y;
        s_t[row][c4 + 2] = v.z; s_t[row][c4 + 3] = v.w;
    }
    __syncthreads();
    int n = tid >> 1, half = (tid & 1) * 16;
#pragma unroll
    for (int j = 0; j < 16; ++j)
        dst[(size_t)n * K + k0 + half + j] = f2bf(s_t[half + j][n]);
}

// ---- kA: per-batch stage, 16 batches/block, 512 threads (8 waves x 16-col slice) -------
// hpt from hp (single coalesced read), then preds/gates/cvec/fusion all in-block.
__global__ __launch_bounds__(512) void kA_stage(
    const float* __restrict__ inp, const float* __restrict__ hp,
    const float* __restrict__ ob, const float* __restrict__ tgb,
    const float* __restrict__ agb, const float* __restrict__ hgb,
    const float* __restrict__ g3b, const float* __restrict__ tw,
    const float* __restrict__ aw, const float* __restrict__ hw,
    const float* __restrict__ wf, const float* __restrict__ bias, WS w) {
    __shared__ __align__(16) u16 s_hpt[16][136], s_ie[16][136], s_top[16][136];
    __shared__ __align__(16) u16 s_g[3][16][136];
    __shared__ float s_corr[16][64];
    __shared__ float s_scal[16][4];
    __shared__ float s_red[8][16];

    int tid = threadIdx.x;
    int b0 = blockIdx.x * 16;

    // StageA: corr, ie, topic, scal (scalar loads; inp rows are not 16B-aligned)
    for (int i = tid; i < 1024; i += 512) {
        int bl = i >> 6, m = i & 63;
        s_corr[bl][m] = inp[(size_t)(b0 + bl) * IN_W + 128 + m];
    }
    {
        int bl = tid >> 5, c4 = (tid & 31) * 4;
        const float* row = inp + (size_t)(b0 + bl) * IN_W;
#pragma unroll
        for (int j = 0; j < 4; ++j) s_ie[bl][c4 + j] = f2bf(row[c4 + j]);
#pragma unroll
        for (int j = 0; j < 4; ++j) s_top[bl][c4 + j] = f2bf(row[192 + c4 + j]);
    }
    if (tid < 64) {
        int bl = tid >> 2, j = tid & 3;
        if (j < 3) s_scal[bl][j] = inp[(size_t)(b0 + bl) * IN_W + 320 + j];
    }
    __syncthreads();

    // Phase0: hpt[bl][n] = sum_m corr[m] * hp[bl][m][n]
    {
        int bl = tid >> 5, c4 = (tid & 31) * 4;
        const float* hpb = hp + (size_t)(b0 + bl) * 8192 + c4;
        float a0 = 0, a1 = 0, a2 = 0, a3 = 0;
#pragma unroll 8
        for (int m = 0; m < 64; ++m) {
            float cr = s_corr[bl][m];
            float4 v = *(const float4*)(hpb + m * 128);
            a0 += cr * v.x; a1 += cr * v.y; a2 += cr * v.z; a3 += cr * v.w;
        }
        s_hpt[bl][c4] = f2bf(a0); s_hpt[bl][c4 + 1] = f2bf(a1);
        s_hpt[bl][c4 + 2] = f2bf(a2); s_hpt[bl][c4 + 3] = f2bf(a3);
    }
    __syncthreads();

    int wv = tid >> 6, l = tid & 63, lr = l & 15, lg_ = l >> 4;
    int n = wv * 16 + lr;

    // preds partial (this wave's 16 cols)
    {
        f32x4 acc = {0.f, 0.f, 0.f, 0.f};
#pragma unroll
        for (int k0 = 0; k0 < 256; k0 += 32) {
            const u16* Ar = (k0 < 128) ? &s_hpt[lr][k0 + lg_ * 8]
                                       : &s_top[lr][(k0 - 128) + lg_ * 8];
            short8 a = *(const short8*)Ar;
            short8 b = *(const short8*)(w.oWb + (size_t)n * 256 + k0 + lg_ * 8);
            acc = MFMA16(a, b, acc);
        }
        float obn = ob[n];
        float s[4];
#pragma unroll
        for (int rr = 0; rr < 4; ++rr) s[rr] = sigmoidf_(acc[rr] + obn);
#pragma unroll
        for (int off = 1; off <= 8; off <<= 1)
#pragma unroll
            for (int rr = 0; rr < 4; ++rr) s[rr] += __shfl_xor(s[rr], off);
        if (lr == 0)
#pragma unroll
            for (int rr = 0; rr < 4; ++rr) s_red[wv][lg_ * 4 + rr] = s[rr];
    }

    // gates -> s_g (bf16, LDS only)
    {
        const float* GB[3] = {tgb, agb, hgb};
        const u16* GW[3] = {w.tgWb, w.agWb, w.hgWb};
#pragma unroll
        for (int g = 0; g < 3; ++g) {
            f32x4 acc = {0.f, 0.f, 0.f, 0.f};
#pragma unroll
            for (int k0 = 0; k0 < 256; k0 += 32) {
                const u16* Ar = (k0 < 128) ? &s_hpt[lr][k0 + lg_ * 8]
                                           : &s_ie[lr][(k0 - 128) + lg_ * 8];
                short8 a = *(const short8*)Ar;
                short8 b = *(const short8*)(GW[g] + (size_t)n * 256 + k0 + lg_ * 8);
                acc = MFMA16(a, b, acc);
            }
            float gbn = GB[g][n];
#pragma unroll
            for (int rr = 0; rr < 4; ++rr) {
                int bl = lg_ * 4 + rr;
                float gf = 0.3f + 0.7f * sigmoidf_(10.f * (s_scal[bl][g] - 0.3f));
                s_g[g][bl][n] = f2bf(sigmoidf_((acc[rr] + gbn) * gf));
            }
        }
    }

    // cvec = ie @ g3W2 + scalars*wsum + g3b (f32 to ws)
    {
        f32x4 acc = {0.f, 0.f, 0.f, 0.f};
#pragma unroll
        for (int k0 = 0; k0 < 128; k0 += 32) {
            short8 a = *(const short8*)&s_ie[lr][k0 + lg_ * 8];
            short8 b = *(const short8*)(w.g3W2b + (size_t)n * 128 + k0 + lg_ * 8);
            acc = MFMA16(a, b, acc);
        }
        float wst = w.wsum[n], wsa = w.wsum[128 + n], wsh = w.wsum[256 + n];
        float gbn = g3b[n];
#pragma unroll
        for (int rr = 0; rr < 4; ++rr) {
            int bl = lg_ * 4 + rr;
            w.cvec[(size_t)(b0 + bl) * 128 + n] =
                acc[rr] + s_scal[bl][0] * wst + s_scal[bl][1] * wsa + s_scal[bl][2] * wsh + gbn;
        }
    }
    __syncthreads();

    // fusion: sum_r wf[r] * prod_g (gains_g @ fW[g][r] + pad) -> relu(+bias) -> lg
    {
        float lgacc[4] = {0.f, 0.f, 0.f, 0.f};
#pragma unroll
        for (int r = 0; r < 4; ++r) {
            f32x4 F[3];
#pragma unroll
            for (int g = 0; g < 3; ++g) {
                f32x4 acc = {0.f, 0.f, 0.f, 0.f};
                const u16* Bg = w.fWb + (size_t)(g * 4 + r) * 16384;
#pragma unroll
                for (int k0 = 0; k0 < 128; k0 += 32) {
                    short8 a = *(const short8*)&s_g[g][lr][k0 + lg_ * 8];
                    short8 b = *(const short8*)(Bg + (size_t)n * 128 + k0 + lg_ * 8);
                    acc = MFMA16(a, b, acc);
                }
                const float* pad = (g == 0 ? tw : g == 1 ? aw : hw) + (size_t)(r * 129 + 128) * 128;
                float pv = pad[n];
#pragma unroll
                for (int rr = 0; rr < 4; ++rr) F[g][rr] = acc[rr] + pv;
            }
            float wfr = wf[r];
#pragma unroll
            for (int rr = 0; rr < 4; ++rr) lgacc[rr] += wfr * F[0][rr] * F[1][rr] * F[2][rr];
        }
        float bn = bias[n];
#pragma unroll
        for (int rr = 0; rr < 4; ++rr)
            w.lg[(size_t)(b0 + lg_ * 4 + rr) * 128 + n] = fmaxf(lgacc[rr] + bn, 0.f);
    }

    // preds final
    if (tid < 16) {
        float p = 0.f;
#pragma unroll
        for (int q = 0; q < 8; ++q) p += s_red[q][tid];
        w.preds[b0 + tid] = p * (1.f / 128.f);
    }
}

// ---- k2: forget-gate MFMA GEMM + h epilogue + h_tilde. 4 batches/block, wave=batch ----
__global__ __launch_bounds__(256) void k2_big(const float* __restrict__ inp,
                                              const float* __restrict__ hp, WS w,
                                              float* __restrict__ out_h) {
    __shared__ __align__(16) u16 s_w1[128 * 136];
    __shared__ float s_lg[4][128], s_cv[4][128], s_corr[4][64];
    int tid = threadIdx.x, b0 = blockIdx.x * 4;
    for (int i = tid; i < 2048; i += 256) {
        int row = i >> 4, c8 = (i & 15) * 8;
        *(short8*)(s_w1 + row * 136 + c8) = *(const short8*)(w.W1b + (size_t)row * 128 + c8);
    }
    for (int i = tid; i < 512; i += 256) {
        int bl = i >> 7, c = i & 127;
        s_lg[bl][c] = w.lg[(size_t)(b0 + bl) * 128 + c];
        s_cv[bl][c] = w.cvec[(size_t)(b0 + bl) * 128 + c];
    }
    {
        int bl = tid >> 6, m = tid & 63;
        s_corr[bl][m] = inp[(size_t)(b0 + bl) * IN_W + 128 + m];
    }
    __syncthreads();

    int wv = tid >> 6, l = tid & 63, lr = l & 15, lg_ = l >> 4;
    int b = b0 + wv;
    const float* hpb = hp + (size_t)b * 8192;
    float* outb = out_h + (size_t)b * 8192;
    float csum[8] = {0.f, 0.f, 0.f, 0.f, 0.f, 0.f, 0.f, 0.f};

#pragma unroll
    for (int mt = 0; mt < 4; ++mt) {
        short8 afr[4];
#pragma unroll
        for (int k0i = 0; k0i < 4; ++k0i) {
            const float* p = hpb + (mt * 16 + lr) * 128 + k0i * 32 + lg_ * 8;
            float4 x0 = *(const float4*)p, x1 = *(const float4*)(p + 4);
            BF8 t;
            t.u[0] = f2bf(x0.x); t.u[1] = f2bf(x0.y); t.u[2] = f2bf(x0.z); t.u[3] = f2bf(x0.w);
            t.u[4] = f2bf(x1.x); t.u[5] = f2bf(x1.y); t.u[6] = f2bf(x1.z); t.u[7] = f2bf(x1.w);
            afr[k0i] = t.v;
        }
#pragma unroll
        for (int nt = 0; nt < 8; ++nt) {
            f32x4 acc = {0.f, 0.f, 0.f, 0.f};
#pragma unroll
            for (int k0i = 0; k0i < 4; ++k0i) {
                short8 bv = *(const short8*)(s_w1 + (nt * 16 + lr) * 136 + k0i * 32 + lg_ * 8);
                acc = MFMA16(afr[k0i], bv, acc);
            }
            int n = nt * 16 + lr;
            float cv = s_cv[wv][n], lgv = s_lg[wv][n];
#pragma unroll
            for (int rr = 0; rr < 4; ++rr) {
                int m = mt * 16 + lg_ * 4 + rr;
                float cr = s_corr[wv][m];
                float fg = sigmoidf_(acc[rr] + cv);
                float hv = hpb[m * 128 + n] * fg + cr * lgv;
                outb[m * 128 + n] = hv;
                csum[nt] += cr * hv;
            }
        }
    }
#pragma unroll
    for (int nt = 0; nt < 8; ++nt) {
        float c = csum[nt];
        c += __shfl_xor(c, 16);
        c += __shfl_xor(c, 32);
        if (l < 16) w.htldb[(size_t)b * 128 + nt * 16 + l] = f2bf(c);
    }
}

// ---- k3: after_preds + improve ---------------------------------------------------------
__global__ __launch_bounds__(256) void k3_after(const float* __restrict__ inp,
                                                const float* __restrict__ ob, WS w,
                                                float* __restrict__ out_res) {
    __shared__ float s_red[4][16];
    int tid = threadIdx.x, m0 = blockIdx.x * 16;
    int wv = tid >> 6, l = tid & 63, lr = l & 15, lg_ = l >> 4;
    int ncol0 = wv * 32;
    f32x4 acc0 = {0.f, 0.f, 0.f, 0.f}, acc1 = {0.f, 0.f, 0.f, 0.f};
#pragma unroll
    for (int k0 = 0; k0 < 256; k0 += 32) {
        short8 a;
        if (k0 < 128) {
            a = *(const short8*)(w.htldb + (size_t)(m0 + lr) * 128 + k0 + lg_ * 8);
        } else {
            const float* p = inp + (size_t)(m0 + lr) * IN_W + 192 + (k0 - 128) + lg_ * 8;
            BF8 t;
#pragma unroll
            for (int j = 0; j < 8; ++j) t.u[j] = f2bf(p[j]);
            a = t.v;
        }
        short8 b0v = *(const short8*)(w.oWb + (size_t)(ncol0 + lr) * 256 + k0 + lg_ * 8);
        short8 b1v = *(const short8*)(w.oWb + (size_t)(ncol0 + 16 + lr) * 256 + k0 + lg_ * 8);
        acc0 = MFMA16(a, b0v, acc0);
        acc1 = MFMA16(a, b1v, acc1);
    }
    float s[4];
#pragma unroll
    for (int rr = 0; rr < 4; ++rr)
        s[rr] = sigmoidf_(acc0[rr] + ob[ncol0 + lr]) + sigmoidf_(acc1[rr] + ob[ncol0 + 16 + lr]);
#pragma unroll
    for (int off = 1; off <= 8; off <<= 1)
#pragma unroll
        for (int rr = 0; rr < 4; ++rr) s[rr] += __shfl_xor(s[rr], off);
    if (lr == 0)
#pragma unroll
        for (int rr = 0; rr < 4; ++rr) s_red[wv][lg_ * 4 + rr] = s[rr];
    __syncthreads();
    if (tid < 16) {
        float ap = (s_red[0][tid] + s_red[1][tid] + s_red[2][tid] + s_red[3][tid]) * (1.f / 128.f);
        float p = w.preds[m0 + tid];
        out_res[(size_t)(m0 + tid) * 2] = p;
        out_res[(size_t)(m0 + tid) * 2 + 1] = (ap - p) / (1.f - p);
    }
}

extern "C" void kernel_launch(void* const* d_in, const int* in_sizes, int n_in,
                              void* d_out, int out_size, void* d_ws, size_t ws_size,
                              hipStream_t stream) {
    const float* inp  = (const float*)d_in[0];
    const float* st   = (const float*)d_in[1];
    const float* tw   = (const float*)d_in[2];
    const float* aw   = (const float*)d_in[3];
    const float* hw   = (const float*)d_in[4];
    const float* wf   = (const float*)d_in[5];
    const float* bias = (const float*)d_in[6];
    const float* g3W  = (const float*)d_in[7];
    const float* g3b  = (const float*)d_in[8];
    const float* oW   = (const float*)d_in[9];
    const float* ob   = (const float*)d_in[10];
    const float* tgW  = (const float*)d_in[11];
    const float* tgb  = (const float*)d_in[12];
    const float* agW  = (const float*)d_in[13];
    const float* agb  = (const float*)d_in[14];
    const float* hgW  = (const float*)d_in[15];
    const float* hgb  = (const float*)d_in[16];

    float* out_res = (float*)d_out;                 // (4096, 2)
    float* out_h   = (float*)d_out + 2 * B_TOT;     // (4096, 64, 128)

    char* p = (char*)d_ws;
    auto alloc = [&](size_t bytes) { char* r = p; p += (bytes + 255) & ~255ull; return r; };
    WS w;
    w.oWb   = (u16*)alloc(256 * 128 * 2);
    w.tgWb  = (u16*)alloc(256 * 128 * 2);
    w.agWb  = (u16*)alloc(256 * 128 * 2);
    w.hgWb  = (u16*)alloc(256 * 128 * 2);
    w.g3W2b = (u16*)alloc(128 * 128 * 2);
    w.W1b   = (u16*)alloc(128 * 128 * 2);
    w.fWb   = (u16*)alloc(12 * 128 * 128 * 2);
    w.htldb = (u16*)alloc((size_t)B_TOT * 128 * 2);
    w.wsum  = (float*)alloc(3 * 128 * 4);
    w.preds = (float*)alloc(B_TOT * 4);
    w.cvec  = (float*)alloc((size_t)B_TOT * 128 * 4);
    w.lg    = (float*)alloc((size_t)B_TOT * 128 * 4);

    k0_prep<<<89, 256, 0, stream>>>(oW, tgW, agW, hgW, g3W, tw, aw, hw, w);
    kA_stage<<<B_TOT / 16, 512, 0, stream>>>(inp, st, ob, tgb, agb, hgb, g3b,
                                             tw, aw, hw, wf, bias, w);
    k2_big<<<B_TOT / 4, 256, 0, stream>>>(inp, st, w, out_h);
    k3_after<<<B_TOT / 16, 256, 0, stream>>>(inp, ob, w, out_res);
}